// Round 16
// baseline (203.419 us; speedup 1.0000x reference)
//
#include <hip/hip_runtime.h>
#include <hip/hip_bf16.h>

// Problem dims (compile-time constants from the reference)
#define BB 32
#define SS 128
#define PP 64
#define DD 256
#define HH 128
#define NF 3

// Ledger (measured): pool 45.9 | gru 77 | xg ~23 | attn2 ~19 | gaps ~21.
// This round: gru v11 — r=12/c=8 (halves hq ds_read traffic), 4-level DPP
// fold with flip-disjoint pack bits (bit3 via xor15, bit2 via xor7).

// ---------------------------------------------------------------------------
// Kernel 1: conv-attention pooling (measured 45.9 us, ~93% of HBM floor).
// ---------------------------------------------------------------------------
__global__ __launch_bounds__(256) void k_pool(
    const float* __restrict__ inp,      // [B,S,P,D]
    const float* __restrict__ conv_w,   // [D]
    const float* __restrict__ conv_bp,  // [1]
    float* __restrict__ conv_out,       // [B*S, D]
    float* __restrict__ conv_wts_out)   // [B*S, P]
{
    __shared__ float scores[PP];
    __shared__ float wts[PP];
    __shared__ float4 part4[256];   // 4 KB

    const int bs   = blockIdx.x;      // 0..4095
    const int t    = threadIdx.x;     // 0..255
    const int lane = t & 63;
    const int wv   = t >> 6;

    const float4* src = reinterpret_cast<const float4*>(inp + (size_t)bs * (PP * DD));
    const float4  cw  = reinterpret_cast<const float4*>(conv_w)[lane];
    const float   cb  = conv_bp[0];

    float4 v[16];
#pragma unroll
    for (int i = 0; i < 16; ++i) v[i] = src[i * 256 + t];

    float part[16];
#pragma unroll
    for (int i = 0; i < 16; ++i)
        part[i] = v[i].x * cw.x + v[i].y * cw.y + v[i].z * cw.z + v[i].w * cw.w;

#pragma unroll
    for (int i = 0; i < 16; ++i) {
#pragma unroll
        for (int m = 32; m >= 1; m >>= 1) part[i] += __shfl_xor(part[i], m);
        if (lane == i) scores[i * 4 + wv] = part[i] + cb;
    }
    __syncthreads();

    if (wv == 0) {
        float s = scores[lane];
        float mx = s;
#pragma unroll
        for (int m = 32; m >= 1; m >>= 1) mx = fmaxf(mx, __shfl_xor(mx, m));
        float e = __expf(s - mx);
        float sm = e;
#pragma unroll
        for (int m = 32; m >= 1; m >>= 1) sm += __shfl_xor(sm, m);
        float w = e / sm;
        wts[lane] = w;
        conv_wts_out[(size_t)bs * PP + lane] = w;
    }
    __syncthreads();

    float4 acc = {0.f, 0.f, 0.f, 0.f};
#pragma unroll
    for (int i = 0; i < 16; ++i) {
        const float w = wts[4 * i + wv];
        acc.x = fmaf(w, v[i].x, acc.x);
        acc.y = fmaf(w, v[i].y, acc.y);
        acc.z = fmaf(w, v[i].z, acc.z);
        acc.w = fmaf(w, v[i].w, acc.w);
    }
    part4[t] = acc;
    __syncthreads();

    if (wv == 0) {
        float4 a = part4[lane];
        const float4 b1 = part4[64 + lane];
        const float4 b2 = part4[128 + lane];
        const float4 b3 = part4[192 + lane];
        a.x += b1.x + b2.x + b3.x;
        a.y += b1.y + b2.y + b3.y;
        a.z += b1.z + b2.z + b3.z;
        a.w += b1.w + b2.w + b3.w;
        reinterpret_cast<float4*>(conv_out + (size_t)bs * DD)[lane] = a;
    }
}

// ---------------------------------------------------------------------------
// Kernel 2: xg GEMM (unchanged).
// ---------------------------------------------------------------------------
#define GBM 128
#define GBN 128
#define GBK 32
#define GAS 132

__global__ __launch_bounds__(256) void k_xg(
    const float* __restrict__ A,    // [4096,256]
    const float* __restrict__ Wf,   // [384,256]
    const float* __restrict__ Wb,   // [384,256]
    const float* __restrict__ bf,   // [384]
    const float* __restrict__ bb,   // [384]
    float* __restrict__ xg)         // [4096,768]
{
    __shared__ float as_[GBK * GAS];
    __shared__ float bs_[GBK * GAS];

    const int t  = threadIdx.x;
    const int i0 = blockIdx.x * GBM;
    const int j0 = blockIdx.y * GBN;
    const int tx = t & 15, ty = t >> 4;

    const float* Wsrc = (j0 < 384) ? (Wf + (size_t)j0 * DD) : (Wb + (size_t)(j0 - 384) * DD);
    const float* bsrc = (j0 < 384) ? (bf + j0) : (bb + (j0 - 384));

    float acc[8][8];
#pragma unroll
    for (int ii = 0; ii < 8; ++ii)
#pragma unroll
        for (int jj = 0; jj < 8; ++jj) acc[ii][jj] = 0.f;

    float4 pa[4], pb[4];
#pragma unroll
    for (int p = 0; p < 4; ++p) {
        const int idx = p * 256 + t, r = idx >> 3, k4 = idx & 7;
        pa[p] = *reinterpret_cast<const float4*>(&A[(size_t)(i0 + r) * DD + k4 * 4]);
        pb[p] = *reinterpret_cast<const float4*>(&Wsrc[(size_t)r * DD + k4 * 4]);
    }

    for (int kt = 0; kt < DD; kt += GBK) {
#pragma unroll
        for (int p = 0; p < 4; ++p) {
            const int idx = p * 256 + t, r = idx >> 3, k4 = idx & 7;
            as_[(k4 * 4 + 0) * GAS + r] = pa[p].x;
            as_[(k4 * 4 + 1) * GAS + r] = pa[p].y;
            as_[(k4 * 4 + 2) * GAS + r] = pa[p].z;
            as_[(k4 * 4 + 3) * GAS + r] = pa[p].w;
            bs_[(k4 * 4 + 0) * GAS + r] = pb[p].x;
            bs_[(k4 * 4 + 1) * GAS + r] = pb[p].y;
            bs_[(k4 * 4 + 2) * GAS + r] = pb[p].z;
            bs_[(k4 * 4 + 3) * GAS + r] = pb[p].w;
        }
        __syncthreads();
        if (kt + GBK < DD) {
#pragma unroll
            for (int p = 0; p < 4; ++p) {
                const int idx = p * 256 + t, r = idx >> 3, k4 = idx & 7;
                pa[p] = *reinterpret_cast<const float4*>(&A[(size_t)(i0 + r) * DD + kt + GBK + k4 * 4]);
                pb[p] = *reinterpret_cast<const float4*>(&Wsrc[(size_t)r * DD + kt + GBK + k4 * 4]);
            }
        }
#pragma unroll 8
        for (int k = 0; k < GBK; ++k) {
            float a[8], bq[8];
            *reinterpret_cast<float4*>(&a[0])  = *reinterpret_cast<const float4*>(&as_[k * GAS + ty * 8]);
            *reinterpret_cast<float4*>(&a[4])  = *reinterpret_cast<const float4*>(&as_[k * GAS + ty * 8 + 4]);
            *reinterpret_cast<float4*>(&bq[0]) = *reinterpret_cast<const float4*>(&bs_[k * GAS + tx * 4]);
            *reinterpret_cast<float4*>(&bq[4]) = *reinterpret_cast<const float4*>(&bs_[k * GAS + 64 + tx * 4]);
#pragma unroll
            for (int ii = 0; ii < 8; ++ii)
#pragma unroll
                for (int jj = 0; jj < 8; ++jj) acc[ii][jj] += a[ii] * bq[jj];
        }
        __syncthreads();
    }

    float bias[8];
#pragma unroll
    for (int jj = 0; jj < 4; ++jj) {
        bias[jj]     = bsrc[tx * 4 + jj];
        bias[4 + jj] = bsrc[64 + tx * 4 + jj];
    }
#pragma unroll
    for (int ii = 0; ii < 8; ++ii) {
        float* dst = &xg[(size_t)(i0 + ty * 8 + ii) * 768 + j0];
        float4 o0, o1;
        o0.x = acc[ii][0] + bias[0]; o0.y = acc[ii][1] + bias[1];
        o0.z = acc[ii][2] + bias[2]; o0.w = acc[ii][3] + bias[3];
        o1.x = acc[ii][4] + bias[4]; o1.y = acc[ii][5] + bias[5];
        o1.z = acc[ii][6] + bias[6]; o1.w = acc[ii][7] + bias[7];
        reinterpret_cast<float4*>(dst + tx * 4)[0]      = o0;
        reinterpret_cast<float4*>(dst + 64 + tx * 4)[0] = o1;
    }
}

// ---------------------------------------------------------------------------
// Kernel 3: bidirectional GRU recurrence, v11.
// r=12, c=8: thread (g4=tid>>4, p=tid&15) computes 12 row dots
// ({r,z,n} x {g4, g4+32, g4+64, g4+96}) over h[p*8..p*8+8).
// hq traffic: 2 ds_read_b128/thread (16 wave-insts/CU/step, was 32).
// 4-level DPP fold, flip-disjoint pack bits:
//   pack1 (bit3) via row_mirror 0x140 (xor15 -> flips bit3; OK for pack)
//   pack2 (bit2) via row_half_mirror 0x141 (xor7 -> preserves bit3)
//   xor1 (0xB1), xor2 (0x4E) complete (preserve bits 2,3).
// Gate lane (tid&3)==0 owns row-group G = 2*bit2 + bit3; j = g4 + 32*G.
// h padded HSEG8=12 (16B-aligned chunk bases; <=2-way banks = free).
// Fused alpha-score partials at chunk flush (unchanged from v10).
// ---------------------------------------------------------------------------
__device__ __forceinline__ float sigm(float x) { return 1.f / (1.f + __expf(-x)); }
__device__ __forceinline__ float tanh_f(float x) { return 2.f / (1.f + __expf(-2.f * x)) - 1.f; }

template<int CTRL>
__device__ __forceinline__ float dpp_mov(float x) {
    return __int_as_float(__builtin_amdgcn_update_dpp(
        0, __float_as_int(x), CTRL, 0xF, 0xF, true));
}
#define DPP_XOR1 0xB1   // quad_perm [1,0,3,2]
#define DPP_XOR2 0x4E   // quad_perm [2,3,0,1]
#define DPP_HMIR 0x141  // row_half_mirror (xor7 within 8)
#define DPP_MIR  0x140  // row_mirror (xor15 within 16)

#define HSEG8 12   // padded segment stride: h[j] at (j>>3)*HSEG8 + (j&7)
#define CH 16      // steps per xg chunk / states-ring depth
#define XROW 384   // floats per step (3 gates x 128)

__global__ __launch_bounds__(512) void k_gru(
    const float* __restrict__ xg,    // [4096, 768]
    const float* __restrict__ Whf,   // [384,128]
    const float* __restrict__ Whb,   // [384,128]
    const float* __restrict__ bhf,   // [384]
    const float* __restrict__ bhb,   // [384]
    const float* __restrict__ c2w,   // [3, 256]
    float* __restrict__ states,      // [4096, 256]
    float* __restrict__ sc_part)     // [B, 2, NF, SS]
{
    const int blk = blockIdx.x;   // 0..63
    const int b   = blk >> 1;
    const int dir = blk & 1;
    const int tid = threadIdx.x;  // 0..511
    const int g4  = tid >> 4;     // row-group base 0..31
    const int p   = tid & 15;     // h-chunk 0..15 (8 floats each)

    __shared__ float hb[2][16 * HSEG8];   // double-buffered padded h (1.5 KB)
    __shared__ float xs[2][CH * XROW];    // 2 x 24 KB xg chunks
    __shared__ float sring[2][CH][HH];    // 2 x 8 KB states ring

    const float* Wh = dir ? Whb : Whf;
    const float* bh = dir ? bhb : bhf;

    const int  bit2 = (tid >> 2) & 1;
    const int  bit3 = (tid >> 3) & 1;
    const bool gate = (tid & 3) == 0;
    const int  G    = 2 * bit2 + bit3;      // row-group owned by gate lane
    const int  j    = g4 + 32 * G;          // gate row
    float bhr = 0.f, bhz = 0.f, bhn = 0.f;
    if (gate) { bhr = bh[j]; bhz = bh[HH + j]; bhn = bh[2 * HH + j]; }

    // weights: 3 gates x 4 groups x 8 cols = 96 floats (no spill)
    float4 w[3][4][2];
#pragma unroll
    for (int q = 0; q < 3; ++q)
#pragma unroll
        for (int Gi = 0; Gi < 4; ++Gi) {
            const float* row = Wh + (size_t)(q * HH + g4 + 32 * Gi) * HH + p * 8;
            w[q][Gi][0] = *reinterpret_cast<const float4*>(row);
            w[q][Gi][1] = *reinterpret_cast<const float4*>(row + 4);
        }

    const float* xg_bd = xg + (size_t)b * SS * 768 + dir * 384;
    const int hidx = (j >> 3) * HSEG8 + (j & 7);

    float4 pf[3];
    // synchronous stage of chunk 0 (1536 float4 over 512 threads = 3 each)
#pragma unroll
    for (int j3 = 0; j3 < 3; ++j3) {
        const int flat4 = j3 * 512 + tid;      // 0..1535
        const int sic = flat4 / 96, w4 = flat4 % 96;
        const int s = dir ? (SS - 1 - sic) : sic;
        pf[j3] = *reinterpret_cast<const float4*>(xg_bd + (size_t)s * 768 + w4 * 4);
    }
#pragma unroll
    for (int j3 = 0; j3 < 3; ++j3) {
        const int flat4 = j3 * 512 + tid;
        const int sic = flat4 / 96, w4 = flat4 % 96;
        *reinterpret_cast<float4*>(&xs[0][sic * XROW + w4 * 4]) = pf[j3];
    }
    if (tid < 16 * HSEG8) hb[0][tid] = 0.f;
    __syncthreads();
    // issue chunk 1 loads (committed at step 15's boundary)
#pragma unroll
    for (int j3 = 0; j3 < 3; ++j3) {
        const int flat4 = j3 * 512 + tid;
        const int sic = flat4 / 96, w4 = flat4 % 96;
        const int stp = CH + sic;
        const int s = dir ? (SS - 1 - stp) : stp;
        pf[j3] = *reinterpret_cast<const float4*>(xg_bd + (size_t)s * 768 + w4 * 4);
    }

    for (int step = 0; step < SS; ++step) {
        const int cur = step & 1;
        const int sic = step & (CH - 1);
        const int buf = (step >> 4) & 1;

        const float* hrow = hb[cur];
        const float4 h0 = *reinterpret_cast<const float4*>(&hrow[p * HSEG8]);
        const float4 h1 = *reinterpret_cast<const float4*>(&hrow[p * HSEG8 + 4]);

        float hp = 0.f, xrv = 0.f, xzv = 0.f, xnv = 0.f;
        if (gate) {
            hp  = hrow[hidx];
            xrv = xs[buf][sic * XROW + j];
            xzv = xs[buf][sic * XROW + HH + j];
            xnv = xs[buf][sic * XROW + 2 * HH + j];
        }

        // 96 FMA: 12 accumulators x 8 MACs
        float a[3][4];
#pragma unroll
        for (int q = 0; q < 3; ++q)
#pragma unroll
            for (int Gi = 0; Gi < 4; ++Gi) {
                float acc = 0.f;
                acc = fmaf(w[q][Gi][0].x, h0.x, acc);
                acc = fmaf(w[q][Gi][0].y, h0.y, acc);
                acc = fmaf(w[q][Gi][0].z, h0.z, acc);
                acc = fmaf(w[q][Gi][0].w, h0.w, acc);
                acc = fmaf(w[q][Gi][1].x, h1.x, acc);
                acc = fmaf(w[q][Gi][1].y, h1.y, acc);
                acc = fmaf(w[q][Gi][1].z, h1.z, acc);
                acc = fmaf(w[q][Gi][1].w, h1.w, acc);
                a[q][Gi] = acc;
            }

        // 4-level DPP fold:
        // pack1 (bit3, xor15): pair {0,1} and pair {2,3}
        // pack2 (bit2, xor7): A-set vs B-set (preserves bit3)
        // xor1, xor2: complete (preserve bits 2,3)
        float F[3];
#pragma unroll
        for (int q = 0; q < 3; ++q) {
            const float fA = (bit3 ? a[q][1] : a[q][0])
                           + dpp_mov<DPP_MIR>(bit3 ? a[q][0] : a[q][1]);
            const float fB = (bit3 ? a[q][3] : a[q][2])
                           + dpp_mov<DPP_MIR>(bit3 ? a[q][2] : a[q][3]);
            float f = (bit2 ? fB : fA) + dpp_mov<DPP_HMIR>(bit2 ? fA : fB);
            f += dpp_mov<DPP_XOR1>(f);
            f += dpp_mov<DPP_XOR2>(f);
            F[q] = f;
        }

        if (gate) {
            const float r = sigm(xrv + F[0] + bhr);
            const float z = sigm(xzv + F[1] + bhz);
            const float n = tanh_f(xnv + r * (F[2] + bhn));
            const float hnew = (1.f - z) * n + z * hp;
            hb[cur ^ 1][hidx] = hnew;
            sring[buf][sic][j] = hnew;          // LDS ring, not global
        }

        if (sic == CH - 1 && step != SS - 1) {
#pragma unroll
            for (int j3 = 0; j3 < 3; ++j3) {
                const int flat4 = j3 * 512 + tid;
                const int sc = flat4 / 96, w4 = flat4 % 96;
                *reinterpret_cast<float4*>(&xs[buf ^ 1][sc * XROW + w4 * 4]) = pf[j3];
            }
        }
        __syncthreads();

        if (sic == CH - 1) {
            const int cb = (step >> 4) * CH;
            // (a) flush states ring (16 steps x 128 floats = 512 float4)
            {
                const int sic2 = tid >> 5;
                const int off  = (tid & 31) * 4;
                const int st   = cb + sic2;
                const int sO   = dir ? (SS - 1 - st) : st;
                const float4 v4 = *reinterpret_cast<const float4*>(&sring[buf][sic2][off]);
                *reinterpret_cast<float4*>(&states[((size_t)b * SS + sO) * 256 + dir * HH + off]) = v4;
            }
            // (b) alpha-score partials: 48 (f,s) dots of 128 over sring[buf]
            if (tid < 384) {
                const int pair = tid >> 3;     // 0..47
                const int sl   = pair & 15;    // step-in-chunk
                const int f    = pair >> 4;    // filter 0..2
                const int l8   = tid & 7;      // h-sixteenth
                const float4* h4p = reinterpret_cast<const float4*>(&sring[buf][sl][l8 * 16]);
                const float4* w4p = reinterpret_cast<const float4*>(c2w + f * 256 + dir * HH + l8 * 16);
                float aa = 0.f;
#pragma unroll
                for (int k = 0; k < 4; ++k) {
                    const float4 hv = h4p[k], wv4 = w4p[k];
                    aa = fmaf(hv.x, wv4.x, aa); aa = fmaf(hv.y, wv4.y, aa);
                    aa = fmaf(hv.z, wv4.z, aa); aa = fmaf(hv.w, wv4.w, aa);
                }
                aa += dpp_mov<DPP_XOR1>(aa);
                aa += dpp_mov<DPP_XOR2>(aa);
                aa += dpp_mov<DPP_HMIR>(aa);
                if (l8 == 0) {
                    const int st = cb + sl;
                    const int sO = dir ? (SS - 1 - st) : st;
                    sc_part[(((size_t)b * 2 + dir) * NF + f) * SS + sO] = aa;
                }
            }
            // (c) issue loads for chunk+2
            if (step + CH + 1 < SS) {
                const int nchunk = (step >> 4) + 2;
#pragma unroll
                for (int j3 = 0; j3 < 3; ++j3) {
                    const int flat4 = j3 * 512 + tid;
                    const int sc = flat4 / 96, w4 = flat4 % 96;
                    const int st2 = nchunk * CH + sc;
                    const int s2 = dir ? (SS - 1 - st2) : st2;
                    pf[j3] = *reinterpret_cast<const float4*>(xg_bd + (size_t)s2 * 768 + w4 * 4);
                }
            }
        }
    }
}

// ---------------------------------------------------------------------------
// Kernel 4: time attention v2 (unchanged from R15).
// ---------------------------------------------------------------------------
__global__ __launch_bounds__(512) void k_attn2(
    const float* __restrict__ states,   // [B*S, 256]
    const float* __restrict__ sc_part,  // [B, 2, NF, SS]
    const float* __restrict__ c2b,      // [3]
    const float* __restrict__ demoip,   // [B, 3]
    const float* __restrict__ lin_w,    // [2, 771]
    const float* __restrict__ lin_b,    // [2]
    float* __restrict__ out,            // [B, 2]
    float* __restrict__ alpha_out,      // [B, 3, 128]
    float* __restrict__ ctx_out)        // [B, 768]
{
    const int b    = blockIdx.x;
    const int t    = threadIdx.x;      // 0..511
    const int lane = t & 63;
    const int wv   = t >> 6;

    __shared__ float sc[NF * SS];
    __shared__ float al[NF * SS];
    __shared__ float pbuf[8][NF * 256];   // 24 KB partials
    __shared__ float ctx[768];

    const float* st = states + (size_t)b * SS * 256;

    // phase 1: combine precomputed per-dir partials
    if (t < NF * SS) {
        const int f = t >> 7, s = t & 127;
        sc[t] = sc_part[(((size_t)b * 2 + 0) * NF + f) * SS + s]
              + sc_part[(((size_t)b * 2 + 1) * NF + f) * SS + s]
              + c2b[f];
    }
    __syncthreads();

    // phase 2: softmax over s per filter (waves 0..2)
    if (wv < NF) {
        const float v0 = sc[wv * SS + lane], v1 = sc[wv * SS + 64 + lane];
        float mx = fmaxf(v0, v1);
#pragma unroll
        for (int m = 32; m >= 1; m >>= 1) mx = fmaxf(mx, __shfl_xor(mx, m));
        const float e0 = __expf(v0 - mx), e1 = __expf(v1 - mx);
        float sm = e0 + e1;
#pragma unroll
        for (int m = 32; m >= 1; m >>= 1) sm += __shfl_xor(sm, m);
        const float r = 1.f / sm;
        al[wv * SS + lane]      = e0 * r;
        al[wv * SS + 64 + lane] = e1 * r;
        alpha_out[((size_t)b * NF + wv) * SS + lane]      = e0 * r;
        alpha_out[((size_t)b * NF + wv) * SS + 64 + lane] = e1 * r;
    }
    __syncthreads();

    // phase 3: context partials. thread = (grp = t>>6 over 16 s, h4 = t&63)
    {
        const int grp = t >> 6, h4 = t & 63;
        float4 c0 = {0,0,0,0}, c1 = {0,0,0,0}, c2 = {0,0,0,0};
#pragma unroll 4
        for (int i = 0; i < 16; ++i) {
            const int s = grp * 16 + i;
            const float4 sv = *reinterpret_cast<const float4*>(st + (size_t)s * 256 + h4 * 4);
            const float a0 = al[s], a1 = al[SS + s], a2 = al[2 * SS + s];
            c0.x = fmaf(a0, sv.x, c0.x); c0.y = fmaf(a0, sv.y, c0.y);
            c0.z = fmaf(a0, sv.z, c0.z); c0.w = fmaf(a0, sv.w, c0.w);
            c1.x = fmaf(a1, sv.x, c1.x); c1.y = fmaf(a1, sv.y, c1.y);
            c1.z = fmaf(a1, sv.z, c1.z); c1.w = fmaf(a1, sv.w, c1.w);
            c2.x = fmaf(a2, sv.x, c2.x); c2.y = fmaf(a2, sv.y, c2.y);
            c2.z = fmaf(a2, sv.z, c2.z); c2.w = fmaf(a2, sv.w, c2.w);
        }
        *reinterpret_cast<float4*>(&pbuf[grp][0 * 256 + h4 * 4]) = c0;
        *reinterpret_cast<float4*>(&pbuf[grp][1 * 256 + h4 * 4]) = c1;
        *reinterpret_cast<float4*>(&pbuf[grp][2 * 256 + h4 * 4]) = c2;
    }
    __syncthreads();

    for (int o = t; o < 768; o += 512) {
        float v = 0.f;
#pragma unroll
        for (int k = 0; k < 8; ++k) v += pbuf[k][o];
        ctx[o] = v;
        ctx_out[(size_t)b * 768 + o] = v;
    }
    __syncthreads();

    // phase 4: final linear (771 -> 2) + softmax, wave-parallel on wave 0
    if (wv == 0) {
        const float* lw0 = lin_w;          // row 0
        const float* lw1 = lin_w + 771;    // row 1
        float a0 = 0.f, a1 = 0.f;
#pragma unroll 4
        for (int i = lane; i < 768; i += 64) {
            const float c = ctx[i];
            a0 = fmaf(c, lw0[i], a0);
            a1 = fmaf(c, lw1[i], a1);
        }
#pragma unroll
        for (int m = 32; m >= 1; m >>= 1) {
            a0 += __shfl_xor(a0, m);
            a1 += __shfl_xor(a1, m);
        }
        if (lane == 0) {
            a0 += lin_b[0]; a1 += lin_b[1];
            for (int k = 0; k < 3; ++k) {
                const float d = demoip[b * 3 + k];
                a0 = fmaf(d, lw0[768 + k], a0);
                a1 = fmaf(d, lw1[768 + k], a1);
            }
            const float m  = fmaxf(a0, a1);
            const float e0 = __expf(a0 - m), e1 = __expf(a1 - m);
            const float s  = e0 + e1;
            out[b * 2 + 0] = e0 / s;
            out[b * 2 + 1] = e1 / s;
        }
    }
}

// ---------------------------------------------------------------------------
extern "C" void kernel_launch(void* const* d_in, const int* in_sizes, int n_in,
                              void* d_out, int out_size, void* d_ws, size_t ws_size,
                              hipStream_t stream) {
    const float* inp     = (const float*)d_in[0];
    const float* demoip  = (const float*)d_in[1];
    const float* conv_w  = (const float*)d_in[2];
    const float* conv_b  = (const float*)d_in[3];
    const float* c2w     = (const float*)d_in[4];
    const float* c2b     = (const float*)d_in[5];
    const float* Wih_f   = (const float*)d_in[6];
    const float* Whh_f   = (const float*)d_in[7];
    const float* bih_f   = (const float*)d_in[8];
    const float* bhh_f   = (const float*)d_in[9];
    const float* Wih_b   = (const float*)d_in[10];
    const float* Whh_b   = (const float*)d_in[11];
    const float* bih_b   = (const float*)d_in[12];
    const float* bhh_b   = (const float*)d_in[13];
    const float* lin_w   = (const float*)d_in[14];
    const float* lin_b   = (const float*)d_in[15];

    // d_out layout: out[64] | alpha[12288] | states[1048576] | context[24576] | conv_wts[262144]
    float* out      = (float*)d_out;
    float* alpha    = out + 64;
    float* states   = out + 12352;
    float* context  = out + 1060928;
    float* conv_wts = out + 1085504;

    // workspace: conv_out [4096*256] | xg [4096*768] (exactly 16 MiB).
    // sc_part overlays conv_out (disjoint lifetimes).
    float* conv_out = (float*)d_ws;
    float* xg       = conv_out + (size_t)4096 * 256;
    float* sc_part  = conv_out;

    k_pool<<<dim3(BB * SS), dim3(256), 0, stream>>>(inp, conv_w, conv_b, conv_out, conv_wts);
    k_xg<<<dim3(4096 / GBM, 768 / GBN), dim3(256), 0, stream>>>(conv_out, Wih_f, Wih_b, bih_f, bih_b, xg);
    k_gru<<<dim3(64), dim3(512), 0, stream>>>(xg, Whh_f, Whh_b, bhh_f, bhh_b, c2w, states, sc_part);
    k_attn2<<<dim3(BB), dim3(512), 0, stream>>>(states, sc_part, c2b, demoip, lin_w, lin_b, out, alpha, context);
}

// Round 17
// 192.344 us; speedup vs baseline: 1.0576x; 1.0576x over previous
//
#include <hip/hip_runtime.h>
#include <hip/hip_bf16.h>

// Problem dims (compile-time constants from the reference)
#define BB 32
#define SS 128
#define PP 64
#define DD 256
#define HH 128
#define NF 3

// Ledger (measured/derived): pool 45.9 | gru 77 | xg ~23 | attn2 ~13 |
// gaps ~21. R16's r=12 gru regressed (+15.6) -> reverted to v10.
// This round: gru v12 = v10 + v_pk_fma_f32 matvec (halves FMA issue).

// ---------------------------------------------------------------------------
// Kernel 1: conv-attention pooling (measured 45.9 us, ~93% of HBM floor).
// ---------------------------------------------------------------------------
__global__ __launch_bounds__(256) void k_pool(
    const float* __restrict__ inp,      // [B,S,P,D]
    const float* __restrict__ conv_w,   // [D]
    const float* __restrict__ conv_bp,  // [1]
    float* __restrict__ conv_out,       // [B*S, D]
    float* __restrict__ conv_wts_out)   // [B*S, P]
{
    __shared__ float scores[PP];
    __shared__ float wts[PP];
    __shared__ float4 part4[256];   // 4 KB

    const int bs   = blockIdx.x;      // 0..4095
    const int t    = threadIdx.x;     // 0..255
    const int lane = t & 63;
    const int wv   = t >> 6;

    const float4* src = reinterpret_cast<const float4*>(inp + (size_t)bs * (PP * DD));
    const float4  cw  = reinterpret_cast<const float4*>(conv_w)[lane];
    const float   cb  = conv_bp[0];

    float4 v[16];
#pragma unroll
    for (int i = 0; i < 16; ++i) v[i] = src[i * 256 + t];

    float part[16];
#pragma unroll
    for (int i = 0; i < 16; ++i)
        part[i] = v[i].x * cw.x + v[i].y * cw.y + v[i].z * cw.z + v[i].w * cw.w;

#pragma unroll
    for (int i = 0; i < 16; ++i) {
#pragma unroll
        for (int m = 32; m >= 1; m >>= 1) part[i] += __shfl_xor(part[i], m);
        if (lane == i) scores[i * 4 + wv] = part[i] + cb;
    }
    __syncthreads();

    if (wv == 0) {
        float s = scores[lane];
        float mx = s;
#pragma unroll
        for (int m = 32; m >= 1; m >>= 1) mx = fmaxf(mx, __shfl_xor(mx, m));
        float e = __expf(s - mx);
        float sm = e;
#pragma unroll
        for (int m = 32; m >= 1; m >>= 1) sm += __shfl_xor(sm, m);
        float w = e / sm;
        wts[lane] = w;
        conv_wts_out[(size_t)bs * PP + lane] = w;
    }
    __syncthreads();

    float4 acc = {0.f, 0.f, 0.f, 0.f};
#pragma unroll
    for (int i = 0; i < 16; ++i) {
        const float w = wts[4 * i + wv];
        acc.x = fmaf(w, v[i].x, acc.x);
        acc.y = fmaf(w, v[i].y, acc.y);
        acc.z = fmaf(w, v[i].z, acc.z);
        acc.w = fmaf(w, v[i].w, acc.w);
    }
    part4[t] = acc;
    __syncthreads();

    if (wv == 0) {
        float4 a = part4[lane];
        const float4 b1 = part4[64 + lane];
        const float4 b2 = part4[128 + lane];
        const float4 b3 = part4[192 + lane];
        a.x += b1.x + b2.x + b3.x;
        a.y += b1.y + b2.y + b3.y;
        a.z += b1.z + b2.z + b3.z;
        a.w += b1.w + b2.w + b3.w;
        reinterpret_cast<float4*>(conv_out + (size_t)bs * DD)[lane] = a;
    }
}

// ---------------------------------------------------------------------------
// Kernel 2: xg GEMM (unchanged).
// ---------------------------------------------------------------------------
#define GBM 128
#define GBN 128
#define GBK 32
#define GAS 132

__global__ __launch_bounds__(256) void k_xg(
    const float* __restrict__ A,    // [4096,256]
    const float* __restrict__ Wf,   // [384,256]
    const float* __restrict__ Wb,   // [384,256]
    const float* __restrict__ bf,   // [384]
    const float* __restrict__ bb,   // [384]
    float* __restrict__ xg)         // [4096,768]
{
    __shared__ float as_[GBK * GAS];
    __shared__ float bs_[GBK * GAS];

    const int t  = threadIdx.x;
    const int i0 = blockIdx.x * GBM;
    const int j0 = blockIdx.y * GBN;
    const int tx = t & 15, ty = t >> 4;

    const float* Wsrc = (j0 < 384) ? (Wf + (size_t)j0 * DD) : (Wb + (size_t)(j0 - 384) * DD);
    const float* bsrc = (j0 < 384) ? (bf + j0) : (bb + (j0 - 384));

    float acc[8][8];
#pragma unroll
    for (int ii = 0; ii < 8; ++ii)
#pragma unroll
        for (int jj = 0; jj < 8; ++jj) acc[ii][jj] = 0.f;

    float4 pa[4], pb[4];
#pragma unroll
    for (int p = 0; p < 4; ++p) {
        const int idx = p * 256 + t, r = idx >> 3, k4 = idx & 7;
        pa[p] = *reinterpret_cast<const float4*>(&A[(size_t)(i0 + r) * DD + k4 * 4]);
        pb[p] = *reinterpret_cast<const float4*>(&Wsrc[(size_t)r * DD + k4 * 4]);
    }

    for (int kt = 0; kt < DD; kt += GBK) {
#pragma unroll
        for (int p = 0; p < 4; ++p) {
            const int idx = p * 256 + t, r = idx >> 3, k4 = idx & 7;
            as_[(k4 * 4 + 0) * GAS + r] = pa[p].x;
            as_[(k4 * 4 + 1) * GAS + r] = pa[p].y;
            as_[(k4 * 4 + 2) * GAS + r] = pa[p].z;
            as_[(k4 * 4 + 3) * GAS + r] = pa[p].w;
            bs_[(k4 * 4 + 0) * GAS + r] = pb[p].x;
            bs_[(k4 * 4 + 1) * GAS + r] = pb[p].y;
            bs_[(k4 * 4 + 2) * GAS + r] = pb[p].z;
            bs_[(k4 * 4 + 3) * GAS + r] = pb[p].w;
        }
        __syncthreads();
        if (kt + GBK < DD) {
#pragma unroll
            for (int p = 0; p < 4; ++p) {
                const int idx = p * 256 + t, r = idx >> 3, k4 = idx & 7;
                pa[p] = *reinterpret_cast<const float4*>(&A[(size_t)(i0 + r) * DD + kt + GBK + k4 * 4]);
                pb[p] = *reinterpret_cast<const float4*>(&Wsrc[(size_t)r * DD + kt + GBK + k4 * 4]);
            }
        }
#pragma unroll 8
        for (int k = 0; k < GBK; ++k) {
            float a[8], bq[8];
            *reinterpret_cast<float4*>(&a[0])  = *reinterpret_cast<const float4*>(&as_[k * GAS + ty * 8]);
            *reinterpret_cast<float4*>(&a[4])  = *reinterpret_cast<const float4*>(&as_[k * GAS + ty * 8 + 4]);
            *reinterpret_cast<float4*>(&bq[0]) = *reinterpret_cast<const float4*>(&bs_[k * GAS + tx * 4]);
            *reinterpret_cast<float4*>(&bq[4]) = *reinterpret_cast<const float4*>(&bs_[k * GAS + 64 + tx * 4]);
#pragma unroll
            for (int ii = 0; ii < 8; ++ii)
#pragma unroll
                for (int jj = 0; jj < 8; ++jj) acc[ii][jj] += a[ii] * bq[jj];
        }
        __syncthreads();
    }

    float bias[8];
#pragma unroll
    for (int jj = 0; jj < 4; ++jj) {
        bias[jj]     = bsrc[tx * 4 + jj];
        bias[4 + jj] = bsrc[64 + tx * 4 + jj];
    }
#pragma unroll
    for (int ii = 0; ii < 8; ++ii) {
        float* dst = &xg[(size_t)(i0 + ty * 8 + ii) * 768 + j0];
        float4 o0, o1;
        o0.x = acc[ii][0] + bias[0]; o0.y = acc[ii][1] + bias[1];
        o0.z = acc[ii][2] + bias[2]; o0.w = acc[ii][3] + bias[3];
        o1.x = acc[ii][4] + bias[4]; o1.y = acc[ii][5] + bias[5];
        o1.z = acc[ii][6] + bias[6]; o1.w = acc[ii][7] + bias[7];
        reinterpret_cast<float4*>(dst + tx * 4)[0]      = o0;
        reinterpret_cast<float4*>(dst + 64 + tx * 4)[0] = o1;
    }
}

// ---------------------------------------------------------------------------
// Kernel 3: bidirectional GRU recurrence, v12 = v10 (r=6/c=16, 3-level DPP
// fold, LDS states ring, fused alpha partials) with the matvec issued as
// v_pk_fma_f32 (packed 2xfp32 FMA): 96 scalar FMA -> 48 pk_fma + 6 adds.
// ---------------------------------------------------------------------------
__device__ __forceinline__ float sigm(float x) { return 1.f / (1.f + __expf(-x)); }
__device__ __forceinline__ float tanh_f(float x) { return 2.f / (1.f + __expf(-2.f * x)) - 1.f; }

template<int CTRL>
__device__ __forceinline__ float dpp_mov(float x) {
    return __int_as_float(__builtin_amdgcn_update_dpp(
        0, __float_as_int(x), CTRL, 0xF, 0xF, true));
}
#define DPP_XOR1 0xB1   // quad_perm [1,0,3,2]
#define DPP_XOR2 0x4E   // quad_perm [2,3,0,1]
#define DPP_HMIR 0x141  // row_half_mirror (xor7 within 8)

__device__ __forceinline__ void pk_fma(float2& acc, const float2 a, const float2 b) {
    asm("v_pk_fma_f32 %0, %1, %2, %0" : "+v"(acc) : "v"(a), "v"(b));
}

#define HSEG16 20  // padded segment stride: h[j] at (j>>4)*HSEG16 + (j&15)
#define CH 16      // steps per xg chunk / states-ring depth
#define XROW 384   // floats per step (3 gates x 128)

__global__ __launch_bounds__(512) void k_gru(
    const float* __restrict__ xg,    // [4096, 768]
    const float* __restrict__ Whf,   // [384,128]
    const float* __restrict__ Whb,   // [384,128]
    const float* __restrict__ bhf,   // [384]
    const float* __restrict__ bhb,   // [384]
    const float* __restrict__ c2w,   // [3, 256]
    float* __restrict__ states,      // [4096, 256]
    float* __restrict__ sc_part)     // [B, 2, NF, SS]
{
    const int blk = blockIdx.x;   // 0..63
    const int b   = blk >> 1;
    const int dir = blk & 1;
    const int tid = threadIdx.x;  // 0..511
    const int g   = tid >> 3;     // row-group 0..63
    const int p   = tid & 7;      // h-chunk 0..7

    __shared__ float hb[2][8 * HSEG16];   // double-buffered padded h (1.25 KB)
    __shared__ float xs[2][CH * XROW];    // 2 x 24 KB xg chunks
    __shared__ float sring[2][CH][HH];    // 2 x 8 KB states ring

    const float* Wh = dir ? Whb : Whf;
    const float* bh = dir ? bhb : bhf;

    const int j = g + 64 * ((p >> 2) & 1);   // gate row owned by (p&3)==0 lanes
    const bool gate = (p & 3) == 0;
    float bhr = 0.f, bhz = 0.f, bhn = 0.f;
    if (gate) { bhr = bh[j]; bhz = bh[HH + j]; bhn = bh[2 * HH + j]; }

    // weights: 6 rows x 16-chunk = 96 floats in VGPRs (no spill)
    float4 wra[4], wrb[4], wza[4], wzb[4], wna[4], wnb[4];
    {
        const float4* p_ra = reinterpret_cast<const float4*>(Wh + (size_t)g * HH + p * 16);
        const float4* p_rb = reinterpret_cast<const float4*>(Wh + (size_t)(g + 64) * HH + p * 16);
        const float4* p_za = reinterpret_cast<const float4*>(Wh + (size_t)(HH + g) * HH + p * 16);
        const float4* p_zb = reinterpret_cast<const float4*>(Wh + (size_t)(HH + g + 64) * HH + p * 16);
        const float4* p_na = reinterpret_cast<const float4*>(Wh + (size_t)(2 * HH + g) * HH + p * 16);
        const float4* p_nb = reinterpret_cast<const float4*>(Wh + (size_t)(2 * HH + g + 64) * HH + p * 16);
#pragma unroll
        for (int k = 0; k < 4; ++k) {
            wra[k] = p_ra[k]; wrb[k] = p_rb[k];
            wza[k] = p_za[k]; wzb[k] = p_zb[k];
            wna[k] = p_na[k]; wnb[k] = p_nb[k];
        }
    }

    const float* xg_bd = xg + (size_t)b * SS * 768 + dir * 384;
    const int hidx = (j >> 4) * HSEG16 + (j & 15);

    float4 pf[3];
    // synchronous stage of chunk 0 (1536 float4 over 512 threads = 3 each)
#pragma unroll
    for (int j3 = 0; j3 < 3; ++j3) {
        const int flat4 = j3 * 512 + tid;      // 0..1535
        const int sic = flat4 / 96, w4 = flat4 % 96;
        const int s = dir ? (SS - 1 - sic) : sic;
        pf[j3] = *reinterpret_cast<const float4*>(xg_bd + (size_t)s * 768 + w4 * 4);
    }
#pragma unroll
    for (int j3 = 0; j3 < 3; ++j3) {
        const int flat4 = j3 * 512 + tid;
        const int sic = flat4 / 96, w4 = flat4 % 96;
        *reinterpret_cast<float4*>(&xs[0][sic * XROW + w4 * 4]) = pf[j3];
    }
    if (tid < 8 * HSEG16) hb[0][tid] = 0.f;
    __syncthreads();
    // issue chunk 1 loads (committed at step 15's boundary)
#pragma unroll
    for (int j3 = 0; j3 < 3; ++j3) {
        const int flat4 = j3 * 512 + tid;
        const int sic = flat4 / 96, w4 = flat4 % 96;
        const int stp = CH + sic;
        const int s = dir ? (SS - 1 - stp) : stp;
        pf[j3] = *reinterpret_cast<const float4*>(xg_bd + (size_t)s * 768 + w4 * 4);
    }

    for (int step = 0; step < SS; ++step) {
        const int cur = step & 1;
        const int sic = step & (CH - 1);
        const int buf = (step >> 4) & 1;

        const float* hrow = hb[cur];
        float4 hq[4];
#pragma unroll
        for (int k = 0; k < 4; ++k)
            hq[k] = *reinterpret_cast<const float4*>(&hrow[p * HSEG16 + k * 4]);

        float hp = 0.f, xrv = 0.f, xzv = 0.f, xnv = 0.f;
        if (gate) {
            hp  = hrow[hidx];
            xrv = xs[buf][sic * XROW + j];
            xzv = xs[buf][sic * XROW + HH + j];
            xnv = xs[buf][sic * XROW + 2 * HH + j];
        }

        // matvec: 48 v_pk_fma_f32 (6 accumulators x 8 packed MACs)
        const float2* h2   = reinterpret_cast<const float2*>(hq);
        const float2* wra2 = reinterpret_cast<const float2*>(wra);
        const float2* wrb2 = reinterpret_cast<const float2*>(wrb);
        const float2* wza2 = reinterpret_cast<const float2*>(wza);
        const float2* wzb2 = reinterpret_cast<const float2*>(wzb);
        const float2* wna2 = reinterpret_cast<const float2*>(wna);
        const float2* wnb2 = reinterpret_cast<const float2*>(wnb);
        float2 c_ra = {0.f, 0.f}, c_rb = {0.f, 0.f};
        float2 c_za = {0.f, 0.f}, c_zb = {0.f, 0.f};
        float2 c_na = {0.f, 0.f}, c_nb = {0.f, 0.f};
#pragma unroll
        for (int k = 0; k < 8; ++k) {
            const float2 hk = h2[k];
            pk_fma(c_ra, wra2[k], hk);
            pk_fma(c_rb, wrb2[k], hk);
            pk_fma(c_za, wza2[k], hk);
            pk_fma(c_zb, wzb2[k], hk);
            pk_fma(c_na, wna2[k], hk);
            pk_fma(c_nb, wnb2[k], hk);
        }
        const float a_ra = c_ra.x + c_ra.y, a_rb = c_rb.x + c_rb.y;
        const float a_za = c_za.x + c_za.y, a_zb = c_zb.x + c_zb.y;
        const float a_na = c_na.x + c_na.y, a_nb = c_nb.x + c_nb.y;

        // 3-level DPP fold, bit2-ownership (VALU pipe, no LDS ops)
        const bool own_b = (tid & 4) != 0;
        const float s_r = own_b ? a_ra : a_rb;
        const float s_z = own_b ? a_za : a_zb;
        const float s_n = own_b ? a_na : a_nb;
        float f_r = (own_b ? a_rb : a_ra) + dpp_mov<DPP_HMIR>(s_r);
        float f_z = (own_b ? a_zb : a_za) + dpp_mov<DPP_HMIR>(s_z);
        float f_n = (own_b ? a_nb : a_na) + dpp_mov<DPP_HMIR>(s_n);
        f_r += dpp_mov<DPP_XOR1>(f_r);
        f_z += dpp_mov<DPP_XOR1>(f_z);
        f_n += dpp_mov<DPP_XOR1>(f_n);
        f_r += dpp_mov<DPP_XOR2>(f_r);
        f_z += dpp_mov<DPP_XOR2>(f_z);
        f_n += dpp_mov<DPP_XOR2>(f_n);

        if (gate) {
            const float r = sigm(xrv + f_r + bhr);
            const float z = sigm(xzv + f_z + bhz);
            const float n = tanh_f(xnv + r * (f_n + bhn));
            const float hnew = (1.f - z) * n + z * hp;
            hb[cur ^ 1][hidx] = hnew;
            sring[buf][sic][j] = hnew;          // LDS ring, not global
        }

        if (sic == CH - 1 && step != SS - 1) {
#pragma unroll
            for (int j3 = 0; j3 < 3; ++j3) {
                const int flat4 = j3 * 512 + tid;
                const int sc = flat4 / 96, w4 = flat4 % 96;
                *reinterpret_cast<float4*>(&xs[buf ^ 1][sc * XROW + w4 * 4]) = pf[j3];
            }
        }
        __syncthreads();

        if (sic == CH - 1) {
            const int cb = (step >> 4) * CH;
            // (a) flush states ring (16 steps x 128 floats = 512 float4)
            {
                const int sic2 = tid >> 5;
                const int off  = (tid & 31) * 4;
                const int st   = cb + sic2;
                const int sO   = dir ? (SS - 1 - st) : st;
                const float4 v4 = *reinterpret_cast<const float4*>(&sring[buf][sic2][off]);
                *reinterpret_cast<float4*>(&states[((size_t)b * SS + sO) * 256 + dir * HH + off]) = v4;
            }
            // (b) alpha-score partials: 48 (f,s) dots of 128 over sring[buf]
            if (tid < 384) {
                const int pair = tid >> 3;     // 0..47
                const int sl   = pair & 15;    // step-in-chunk
                const int f    = pair >> 4;    // filter 0..2
                const int l8   = tid & 7;      // h-sixteenth
                const float4* h4p = reinterpret_cast<const float4*>(&sring[buf][sl][l8 * 16]);
                const float4* w4p = reinterpret_cast<const float4*>(c2w + f * 256 + dir * HH + l8 * 16);
                float aa = 0.f;
#pragma unroll
                for (int k = 0; k < 4; ++k) {
                    const float4 hv = h4p[k], wv4 = w4p[k];
                    aa = fmaf(hv.x, wv4.x, aa); aa = fmaf(hv.y, wv4.y, aa);
                    aa = fmaf(hv.z, wv4.z, aa); aa = fmaf(hv.w, wv4.w, aa);
                }
                aa += dpp_mov<DPP_XOR1>(aa);
                aa += dpp_mov<DPP_XOR2>(aa);
                aa += dpp_mov<DPP_HMIR>(aa);
                if (l8 == 0) {
                    const int st = cb + sl;
                    const int sO = dir ? (SS - 1 - st) : st;
                    sc_part[(((size_t)b * 2 + dir) * NF + f) * SS + sO] = aa;
                }
            }
            // (c) issue loads for chunk+2
            if (step + CH + 1 < SS) {
                const int nchunk = (step >> 4) + 2;
#pragma unroll
                for (int j3 = 0; j3 < 3; ++j3) {
                    const int flat4 = j3 * 512 + tid;
                    const int sc = flat4 / 96, w4 = flat4 % 96;
                    const int st2 = nchunk * CH + sc;
                    const int s2 = dir ? (SS - 1 - st2) : st2;
                    pf[j3] = *reinterpret_cast<const float4*>(xg_bd + (size_t)s2 * 768 + w4 * 4);
                }
            }
        }
    }
}

// ---------------------------------------------------------------------------
// Kernel 4: time attention v2 (unchanged from R15).
// ---------------------------------------------------------------------------
__global__ __launch_bounds__(512) void k_attn2(
    const float* __restrict__ states,   // [B*S, 256]
    const float* __restrict__ sc_part,  // [B, 2, NF, SS]
    const float* __restrict__ c2b,      // [3]
    const float* __restrict__ demoip,   // [B, 3]
    const float* __restrict__ lin_w,    // [2, 771]
    const float* __restrict__ lin_b,    // [2]
    float* __restrict__ out,            // [B, 2]
    float* __restrict__ alpha_out,      // [B, 3, 128]
    float* __restrict__ ctx_out)        // [B, 768]
{
    const int b    = blockIdx.x;
    const int t    = threadIdx.x;      // 0..511
    const int lane = t & 63;
    const int wv   = t >> 6;

    __shared__ float sc[NF * SS];
    __shared__ float al[NF * SS];
    __shared__ float pbuf[8][NF * 256];   // 24 KB partials
    __shared__ float ctx[768];

    const float* st = states + (size_t)b * SS * 256;

    // phase 1: combine precomputed per-dir partials
    if (t < NF * SS) {
        const int f = t >> 7, s = t & 127;
        sc[t] = sc_part[(((size_t)b * 2 + 0) * NF + f) * SS + s]
              + sc_part[(((size_t)b * 2 + 1) * NF + f) * SS + s]
              + c2b[f];
    }
    __syncthreads();

    // phase 2: softmax over s per filter (waves 0..2)
    if (wv < NF) {
        const float v0 = sc[wv * SS + lane], v1 = sc[wv * SS + 64 + lane];
        float mx = fmaxf(v0, v1);
#pragma unroll
        for (int m = 32; m >= 1; m >>= 1) mx = fmaxf(mx, __shfl_xor(mx, m));
        const float e0 = __expf(v0 - mx), e1 = __expf(v1 - mx);
        float sm = e0 + e1;
#pragma unroll
        for (int m = 32; m >= 1; m >>= 1) sm += __shfl_xor(sm, m);
        const float r = 1.f / sm;
        al[wv * SS + lane]      = e0 * r;
        al[wv * SS + 64 + lane] = e1 * r;
        alpha_out[((size_t)b * NF + wv) * SS + lane]      = e0 * r;
        alpha_out[((size_t)b * NF + wv) * SS + 64 + lane] = e1 * r;
    }
    __syncthreads();

    // phase 3: context partials. thread = (grp = t>>6 over 16 s, h4 = t&63)
    {
        const int grp = t >> 6, h4 = t & 63;
        float4 c0 = {0,0,0,0}, c1 = {0,0,0,0}, c2 = {0,0,0,0};
#pragma unroll 4
        for (int i = 0; i < 16; ++i) {
            const int s = grp * 16 + i;
            const float4 sv = *reinterpret_cast<const float4*>(st + (size_t)s * 256 + h4 * 4);
            const float a0 = al[s], a1 = al[SS + s], a2 = al[2 * SS + s];
            c0.x = fmaf(a0, sv.x, c0.x); c0.y = fmaf(a0, sv.y, c0.y);
            c0.z = fmaf(a0, sv.z, c0.z); c0.w = fmaf(a0, sv.w, c0.w);
            c1.x = fmaf(a1, sv.x, c1.x); c1.y = fmaf(a1, sv.y, c1.y);
            c1.z = fmaf(a1, sv.z, c1.z); c1.w = fmaf(a1, sv.w, c1.w);
            c2.x = fmaf(a2, sv.x, c2.x); c2.y = fmaf(a2, sv.y, c2.y);
            c2.z = fmaf(a2, sv.z, c2.z); c2.w = fmaf(a2, sv.w, c2.w);
        }
        *reinterpret_cast<float4*>(&pbuf[grp][0 * 256 + h4 * 4]) = c0;
        *reinterpret_cast<float4*>(&pbuf[grp][1 * 256 + h4 * 4]) = c1;
        *reinterpret_cast<float4*>(&pbuf[grp][2 * 256 + h4 * 4]) = c2;
    }
    __syncthreads();

    for (int o = t; o < 768; o += 512) {
        float v = 0.f;
#pragma unroll
        for (int k = 0; k < 8; ++k) v += pbuf[k][o];
        ctx[o] = v;
        ctx_out[(size_t)b * 768 + o] = v;
    }
    __syncthreads();

    // phase 4: final linear (771 -> 2) + softmax, wave-parallel on wave 0
    if (wv == 0) {
        const float* lw0 = lin_w;          // row 0
        const float* lw1 = lin_w + 771;    // row 1
        float a0 = 0.f, a1 = 0.f;
#pragma unroll 4
        for (int i = lane; i < 768; i += 64) {
            const float c = ctx[i];
            a0 = fmaf(c, lw0[i], a0);
            a1 = fmaf(c, lw1[i], a1);
        }
#pragma unroll
        for (int m = 32; m >= 1; m >>= 1) {
            a0 += __shfl_xor(a0, m);
            a1 += __shfl_xor(a1, m);
        }
        if (lane == 0) {
            a0 += lin_b[0]; a1 += lin_b[1];
            for (int k = 0; k < 3; ++k) {
                const float d = demoip[b * 3 + k];
                a0 = fmaf(d, lw0[768 + k], a0);
                a1 = fmaf(d, lw1[768 + k], a1);
            }
            const float m  = fmaxf(a0, a1);
            const float e0 = __expf(a0 - m), e1 = __expf(a1 - m);
            const float s  = e0 + e1;
            out[b * 2 + 0] = e0 / s;
            out[b * 2 + 1] = e1 / s;
        }
    }
}

// ---------------------------------------------------------------------------
extern "C" void kernel_launch(void* const* d_in, const int* in_sizes, int n_in,
                              void* d_out, int out_size, void* d_ws, size_t ws_size,
                              hipStream_t stream) {
    const float* inp     = (const float*)d_in[0];
    const float* demoip  = (const float*)d_in[1];
    const float* conv_w  = (const float*)d_in[2];
    const float* conv_b  = (const float*)d_in[3];
    const float* c2w     = (const float*)d_in[4];
    const float* c2b     = (const float*)d_in[5];
    const float* Wih_f   = (const float*)d_in[6];
    const float* Whh_f   = (const float*)d_in[7];
    const float* bih_f   = (const float*)d_in[8];
    const float* bhh_f   = (const float*)d_in[9];
    const float* Wih_b   = (const float*)d_in[10];
    const float* Whh_b   = (const float*)d_in[11];
    const float* bih_b   = (const float*)d_in[12];
    const float* bhh_b   = (const float*)d_in[13];
    const float* lin_w   = (const float*)d_in[14];
    const float* lin_b   = (const float*)d_in[15];

    // d_out layout: out[64] | alpha[12288] | states[1048576] | context[24576] | conv_wts[262144]
    float* out      = (float*)d_out;
    float* alpha    = out + 64;
    float* states   = out + 12352;
    float* context  = out + 1060928;
    float* conv_wts = out + 1085504;

    // workspace: conv_out [4096*256] | xg [4096*768] (exactly 16 MiB).
    // sc_part overlays conv_out (disjoint lifetimes).
    float* conv_out = (float*)d_ws;
    float* xg       = conv_out + (size_t)4096 * 256;
    float* sc_part  = conv_out;

    k_pool<<<dim3(BB * SS), dim3(256), 0, stream>>>(inp, conv_w, conv_b, conv_out, conv_wts);
    k_xg<<<dim3(4096 / GBM, 768 / GBN), dim3(256), 0, stream>>>(conv_out, Wih_f, Wih_b, bih_f, bih_b, xg);
    k_gru<<<dim3(64), dim3(512), 0, stream>>>(xg, Whh_f, Whh_b, bhh_f, bhh_b, c2w, states, sc_part);
    k_attn2<<<dim3(BB), dim3(512), 0, stream>>>(states, sc_part, c2b, demoip, lin_w, lin_b, out, alpha, context);
}

// Round 18
// 163.765 us; speedup vs baseline: 1.2421x; 1.1745x over previous
//
#include <hip/hip_runtime.h>
#include <hip/hip_bf16.h>

// Problem dims (compile-time constants from the reference)
#define BB 32
#define SS 128
#define PP 64
#define DD 256
#define HH 128
#define NF 3

// Ledger: pool 45.9 | gru 77 (structural floor; v11/v12 attempts regressed,
// reverted to v10) | xg ~23 | attn2 ~13 | gaps ~21.
// This round: xg -> bf16 MFMA (16x16x32), conv_out stored as bf16 by k_pool.

typedef __attribute__((ext_vector_type(8))) short short8v;   // 8 bf16
typedef __attribute__((ext_vector_type(4))) float f32x4;

__device__ __forceinline__ unsigned short f2bf(float x) {
    unsigned int u = __float_as_uint(x);
    u = (u + 0x7FFFu + ((u >> 16) & 1u)) >> 16;   // RNE
    return (unsigned short)u;
}

// ---------------------------------------------------------------------------
// Kernel 1: conv-attention pooling (R15 structure; conv now stored as bf16).
// ---------------------------------------------------------------------------
__global__ __launch_bounds__(256) void k_pool(
    const float* __restrict__ inp,      // [B,S,P,D]
    const float* __restrict__ conv_w,   // [D]
    const float* __restrict__ conv_bp,  // [1]
    unsigned short* __restrict__ conv_bf, // [B*S, D] bf16
    float* __restrict__ conv_wts_out)   // [B*S, P]
{
    __shared__ float scores[PP];
    __shared__ float wts[PP];
    __shared__ float4 part4[256];   // 4 KB

    const int bs   = blockIdx.x;      // 0..4095
    const int t    = threadIdx.x;     // 0..255
    const int lane = t & 63;
    const int wv   = t >> 6;

    const float4* src = reinterpret_cast<const float4*>(inp + (size_t)bs * (PP * DD));
    const float4  cw  = reinterpret_cast<const float4*>(conv_w)[lane];
    const float   cb  = conv_bp[0];

    float4 v[16];
#pragma unroll
    for (int i = 0; i < 16; ++i) v[i] = src[i * 256 + t];

    float part[16];
#pragma unroll
    for (int i = 0; i < 16; ++i)
        part[i] = v[i].x * cw.x + v[i].y * cw.y + v[i].z * cw.z + v[i].w * cw.w;

#pragma unroll
    for (int i = 0; i < 16; ++i) {
#pragma unroll
        for (int m = 32; m >= 1; m >>= 1) part[i] += __shfl_xor(part[i], m);
        if (lane == i) scores[i * 4 + wv] = part[i] + cb;
    }
    __syncthreads();

    if (wv == 0) {
        float s = scores[lane];
        float mx = s;
#pragma unroll
        for (int m = 32; m >= 1; m >>= 1) mx = fmaxf(mx, __shfl_xor(mx, m));
        float e = __expf(s - mx);
        float sm = e;
#pragma unroll
        for (int m = 32; m >= 1; m >>= 1) sm += __shfl_xor(sm, m);
        float w = e / sm;
        wts[lane] = w;
        conv_wts_out[(size_t)bs * PP + lane] = w;
    }
    __syncthreads();

    float4 acc = {0.f, 0.f, 0.f, 0.f};
#pragma unroll
    for (int i = 0; i < 16; ++i) {
        const float w = wts[4 * i + wv];
        acc.x = fmaf(w, v[i].x, acc.x);
        acc.y = fmaf(w, v[i].y, acc.y);
        acc.z = fmaf(w, v[i].z, acc.z);
        acc.w = fmaf(w, v[i].w, acc.w);
    }
    part4[t] = acc;
    __syncthreads();

    if (wv == 0) {
        float4 a = part4[lane];
        const float4 b1 = part4[64 + lane];
        const float4 b2 = part4[128 + lane];
        const float4 b3 = part4[192 + lane];
        a.x += b1.x + b2.x + b3.x;
        a.y += b1.y + b2.y + b3.y;
        a.z += b1.z + b2.z + b3.z;
        a.w += b1.w + b2.w + b3.w;
        ushort4 o;
        o.x = f2bf(a.x); o.y = f2bf(a.y); o.z = f2bf(a.z); o.w = f2bf(a.w);
        *reinterpret_cast<ushort4*>(conv_bf + (size_t)bs * DD + lane * 4) = o;
    }
}

// ---------------------------------------------------------------------------
// Kernel 2: xg GEMM via bf16 MFMA. Block (mb,nb) = 256 m-rows x 16 n-cols.
// 4 waves, wave w owns m-rows w*64..+63 (4 tiles of 16). W tile (16x256)
// converted fp32->bf16 into LDS [16][264] (padded, 2-way banks). A-frags
// read straight from conv_bf (L2-resident). 8 K-steps of 32.
// Frag mapping (gfx950 16x16x32): lane l: row/col = l&15, k = (l>>4)*8+j;
// D: col = l&15, row = (l>>4)*4 + reg.
// ---------------------------------------------------------------------------
#define WLDS_P 264

__global__ __launch_bounds__(256) void k_xg(
    const unsigned short* __restrict__ conv_bf, // [4096,256] bf16
    const float* __restrict__ Wf,    // [384,256]
    const float* __restrict__ Wb,    // [384,256]
    const float* __restrict__ bf,    // [384]
    const float* __restrict__ bb,    // [384]
    float* __restrict__ xg)          // [4096,768]
{
    __shared__ unsigned short wlds[16 * WLDS_P];

    const int t  = threadIdx.x;
    const int m0 = blockIdx.x * 256;
    const int n0 = blockIdx.y * 16;

    const float* Wsrc = (n0 < 384) ? (Wf + (size_t)n0 * DD) : (Wb + (size_t)(n0 - 384) * DD);
    const float* bsrc = (n0 < 384) ? (bf + n0) : (bb + (n0 - 384));

    // stage W tile as bf16: thread t -> n = t>>4, k-base = (t&15)*16
    {
        const int n = t >> 4, kb = (t & 15) * 16;
        const float4* src = reinterpret_cast<const float4*>(Wsrc + (size_t)n * DD + kb);
        unsigned short tmp[16];
#pragma unroll
        for (int q = 0; q < 4; ++q) {
            const float4 v = src[q];
            tmp[q * 4 + 0] = f2bf(v.x);
            tmp[q * 4 + 1] = f2bf(v.y);
            tmp[q * 4 + 2] = f2bf(v.z);
            tmp[q * 4 + 3] = f2bf(v.w);
        }
        unsigned short* dst = &wlds[n * WLDS_P + kb];
        *reinterpret_cast<uint4*>(dst)     = *reinterpret_cast<uint4*>(&tmp[0]);
        *reinterpret_cast<uint4*>(dst + 8) = *reinterpret_cast<uint4*>(&tmp[8]);
    }
    __syncthreads();

    const int w    = t >> 6;
    const int l    = t & 63;
    const int lrow = l & 15;
    const int lk8  = (l >> 4) * 8;

    f32x4 acc[4];
#pragma unroll
    for (int mt = 0; mt < 4; ++mt) acc[mt] = (f32x4){0.f, 0.f, 0.f, 0.f};

    const unsigned short* abase = conv_bf + (size_t)(m0 + w * 64 + lrow) * DD + lk8;
    const unsigned short* bbase = &wlds[lrow * WLDS_P + lk8];

#pragma unroll
    for (int k0 = 0; k0 < DD; k0 += 32) {
        const short8v bfrag = *reinterpret_cast<const short8v*>(bbase + k0);
#pragma unroll
        for (int mt = 0; mt < 4; ++mt) {
            const short8v afrag = *reinterpret_cast<const short8v*>(abase + (size_t)mt * 16 * DD + k0);
            acc[mt] = __builtin_amdgcn_mfma_f32_16x16x32_bf16(afrag, bfrag, acc[mt], 0, 0, 0);
        }
    }

    const float bias_c = bsrc[lrow];
    const int   col    = n0 + lrow;
    const int   rbase  = m0 + w * 64 + (l >> 4) * 4;
#pragma unroll
    for (int mt = 0; mt < 4; ++mt)
#pragma unroll
        for (int r = 0; r < 4; ++r)
            xg[(size_t)(rbase + mt * 16 + r) * 768 + col] = acc[mt][r] + bias_c;
}

// ---------------------------------------------------------------------------
// Kernel 3: bidirectional GRU recurrence, v10 (R15 build — best measured).
// ---------------------------------------------------------------------------
__device__ __forceinline__ float sigm(float x) { return 1.f / (1.f + __expf(-x)); }
__device__ __forceinline__ float tanh_f(float x) { return 2.f / (1.f + __expf(-2.f * x)) - 1.f; }

template<int CTRL>
__device__ __forceinline__ float dpp_mov(float x) {
    return __int_as_float(__builtin_amdgcn_update_dpp(
        0, __float_as_int(x), CTRL, 0xF, 0xF, true));
}
#define DPP_XOR1 0xB1   // quad_perm [1,0,3,2]
#define DPP_XOR2 0x4E   // quad_perm [2,3,0,1]
#define DPP_HMIR 0x141  // row_half_mirror (xor7 within 8)

#define HSEG16 20  // padded segment stride: h[j] at (j>>4)*HSEG16 + (j&15)
#define CH 16      // steps per xg chunk / states-ring depth
#define XROW 384   // floats per step (3 gates x 128)

__global__ __launch_bounds__(512) void k_gru(
    const float* __restrict__ xg,    // [4096, 768]
    const float* __restrict__ Whf,   // [384,128]
    const float* __restrict__ Whb,   // [384,128]
    const float* __restrict__ bhf,   // [384]
    const float* __restrict__ bhb,   // [384]
    const float* __restrict__ c2w,   // [3, 256]
    float* __restrict__ states,      // [4096, 256]
    float* __restrict__ sc_part)     // [B, 2, NF, SS]
{
    const int blk = blockIdx.x;   // 0..63
    const int b   = blk >> 1;
    const int dir = blk & 1;
    const int tid = threadIdx.x;  // 0..511
    const int g   = tid >> 3;     // row-group 0..63
    const int p   = tid & 7;      // h-chunk 0..7

    __shared__ float hb[2][8 * HSEG16];   // double-buffered padded h (1.25 KB)
    __shared__ float xs[2][CH * XROW];    // 2 x 24 KB xg chunks
    __shared__ float sring[2][CH][HH];    // 2 x 8 KB states ring

    const float* Wh = dir ? Whb : Whf;
    const float* bh = dir ? bhb : bhf;

    const int j = g + 64 * ((p >> 2) & 1);   // gate row owned by (p&3)==0 lanes
    const bool gate = (p & 3) == 0;
    float bhr = 0.f, bhz = 0.f, bhn = 0.f;
    if (gate) { bhr = bh[j]; bhz = bh[HH + j]; bhn = bh[2 * HH + j]; }

    // weights: 6 rows x 16-chunk = 96 floats in VGPRs (no spill)
    float4 wra[4], wrb[4], wza[4], wzb[4], wna[4], wnb[4];
    {
        const float4* p_ra = reinterpret_cast<const float4*>(Wh + (size_t)g * HH + p * 16);
        const float4* p_rb = reinterpret_cast<const float4*>(Wh + (size_t)(g + 64) * HH + p * 16);
        const float4* p_za = reinterpret_cast<const float4*>(Wh + (size_t)(HH + g) * HH + p * 16);
        const float4* p_zb = reinterpret_cast<const float4*>(Wh + (size_t)(HH + g + 64) * HH + p * 16);
        const float4* p_na = reinterpret_cast<const float4*>(Wh + (size_t)(2 * HH + g) * HH + p * 16);
        const float4* p_nb = reinterpret_cast<const float4*>(Wh + (size_t)(2 * HH + g + 64) * HH + p * 16);
#pragma unroll
        for (int k = 0; k < 4; ++k) {
            wra[k] = p_ra[k]; wrb[k] = p_rb[k];
            wza[k] = p_za[k]; wzb[k] = p_zb[k];
            wna[k] = p_na[k]; wnb[k] = p_nb[k];
        }
    }

    const float* xg_bd = xg + (size_t)b * SS * 768 + dir * 384;
    const int hidx = (j >> 4) * HSEG16 + (j & 15);

    float4 pf[3];
    // synchronous stage of chunk 0 (1536 float4 over 512 threads = 3 each)
#pragma unroll
    for (int j3 = 0; j3 < 3; ++j3) {
        const int flat4 = j3 * 512 + tid;      // 0..1535
        const int sic = flat4 / 96, w4 = flat4 % 96;
        const int s = dir ? (SS - 1 - sic) : sic;
        pf[j3] = *reinterpret_cast<const float4*>(xg_bd + (size_t)s * 768 + w4 * 4);
    }
#pragma unroll
    for (int j3 = 0; j3 < 3; ++j3) {
        const int flat4 = j3 * 512 + tid;
        const int sic = flat4 / 96, w4 = flat4 % 96;
        *reinterpret_cast<float4*>(&xs[0][sic * XROW + w4 * 4]) = pf[j3];
    }
    if (tid < 8 * HSEG16) hb[0][tid] = 0.f;
    __syncthreads();
    // issue chunk 1 loads (committed at step 15's boundary)
#pragma unroll
    for (int j3 = 0; j3 < 3; ++j3) {
        const int flat4 = j3 * 512 + tid;
        const int sic = flat4 / 96, w4 = flat4 % 96;
        const int stp = CH + sic;
        const int s = dir ? (SS - 1 - stp) : stp;
        pf[j3] = *reinterpret_cast<const float4*>(xg_bd + (size_t)s * 768 + w4 * 4);
    }

    for (int step = 0; step < SS; ++step) {
        const int cur = step & 1;
        const int sic = step & (CH - 1);
        const int buf = (step >> 4) & 1;

        const float* hrow = hb[cur];
        float4 hq[4];
#pragma unroll
        for (int k = 0; k < 4; ++k)
            hq[k] = *reinterpret_cast<const float4*>(&hrow[p * HSEG16 + k * 4]);

        float hp = 0.f, xrv = 0.f, xzv = 0.f, xnv = 0.f;
        if (gate) {
            hp  = hrow[hidx];
            xrv = xs[buf][sic * XROW + j];
            xzv = xs[buf][sic * XROW + HH + j];
            xnv = xs[buf][sic * XROW + 2 * HH + j];
        }

        // 96 FMA: 6 accumulators x 16 MACs
        float a_ra = 0.f, a_rb = 0.f, a_za = 0.f, a_zb = 0.f, a_na = 0.f, a_nb = 0.f;
#pragma unroll
        for (int k = 0; k < 4; ++k) {
            const float4 h4 = hq[k];
            a_ra = fmaf(wra[k].x, h4.x, a_ra); a_ra = fmaf(wra[k].y, h4.y, a_ra);
            a_ra = fmaf(wra[k].z, h4.z, a_ra); a_ra = fmaf(wra[k].w, h4.w, a_ra);
            a_rb = fmaf(wrb[k].x, h4.x, a_rb); a_rb = fmaf(wrb[k].y, h4.y, a_rb);
            a_rb = fmaf(wrb[k].z, h4.z, a_rb); a_rb = fmaf(wrb[k].w, h4.w, a_rb);
            a_za = fmaf(wza[k].x, h4.x, a_za); a_za = fmaf(wza[k].y, h4.y, a_za);
            a_za = fmaf(wza[k].z, h4.z, a_za); a_za = fmaf(wza[k].w, h4.w, a_za);
            a_zb = fmaf(wzb[k].x, h4.x, a_zb); a_zb = fmaf(wzb[k].y, h4.y, a_zb);
            a_zb = fmaf(wzb[k].z, h4.z, a_zb); a_zb = fmaf(wzb[k].w, h4.w, a_zb);
            a_na = fmaf(wna[k].x, h4.x, a_na); a_na = fmaf(wna[k].y, h4.y, a_na);
            a_na = fmaf(wna[k].z, h4.z, a_na); a_na = fmaf(wna[k].w, h4.w, a_na);
            a_nb = fmaf(wnb[k].x, h4.x, a_nb); a_nb = fmaf(wnb[k].y, h4.y, a_nb);
            a_nb = fmaf(wnb[k].z, h4.z, a_nb); a_nb = fmaf(wnb[k].w, h4.w, a_nb);
        }

        // 3-level DPP fold, bit2-ownership (VALU pipe, no LDS ops)
        const bool own_b = (tid & 4) != 0;
        const float s_r = own_b ? a_ra : a_rb;
        const float s_z = own_b ? a_za : a_zb;
        const float s_n = own_b ? a_na : a_nb;
        float f_r = (own_b ? a_rb : a_ra) + dpp_mov<DPP_HMIR>(s_r);
        float f_z = (own_b ? a_zb : a_za) + dpp_mov<DPP_HMIR>(s_z);
        float f_n = (own_b ? a_nb : a_na) + dpp_mov<DPP_HMIR>(s_n);
        f_r += dpp_mov<DPP_XOR1>(f_r);
        f_z += dpp_mov<DPP_XOR1>(f_z);
        f_n += dpp_mov<DPP_XOR1>(f_n);
        f_r += dpp_mov<DPP_XOR2>(f_r);
        f_z += dpp_mov<DPP_XOR2>(f_z);
        f_n += dpp_mov<DPP_XOR2>(f_n);

        if (gate) {
            const float r = sigm(xrv + f_r + bhr);
            const float z = sigm(xzv + f_z + bhz);
            const float n = tanh_f(xnv + r * (f_n + bhn));
            const float hnew = (1.f - z) * n + z * hp;
            hb[cur ^ 1][hidx] = hnew;
            sring[buf][sic][j] = hnew;          // LDS ring, not global
        }

        if (sic == CH - 1 && step != SS - 1) {
#pragma unroll
            for (int j3 = 0; j3 < 3; ++j3) {
                const int flat4 = j3 * 512 + tid;
                const int sc = flat4 / 96, w4 = flat4 % 96;
                *reinterpret_cast<float4*>(&xs[buf ^ 1][sc * XROW + w4 * 4]) = pf[j3];
            }
        }
        __syncthreads();

        if (sic == CH - 1) {
            const int cb = (step >> 4) * CH;
            // (a) flush states ring (16 steps x 128 floats = 512 float4)
            {
                const int sic2 = tid >> 5;
                const int off  = (tid & 31) * 4;
                const int st   = cb + sic2;
                const int sO   = dir ? (SS - 1 - st) : st;
                const float4 v4 = *reinterpret_cast<const float4*>(&sring[buf][sic2][off]);
                *reinterpret_cast<float4*>(&states[((size_t)b * SS + sO) * 256 + dir * HH + off]) = v4;
            }
            // (b) alpha-score partials: 48 (f,s) dots of 128 over sring[buf]
            if (tid < 384) {
                const int pair = tid >> 3;     // 0..47
                const int sl   = pair & 15;    // step-in-chunk
                const int f    = pair >> 4;    // filter 0..2
                const int l8   = tid & 7;      // h-sixteenth
                const float4* h4p = reinterpret_cast<const float4*>(&sring[buf][sl][l8 * 16]);
                const float4* w4p = reinterpret_cast<const float4*>(c2w + f * 256 + dir * HH + l8 * 16);
                float aa = 0.f;
#pragma unroll
                for (int k = 0; k < 4; ++k) {
                    const float4 hv = h4p[k], wv4 = w4p[k];
                    aa = fmaf(hv.x, wv4.x, aa); aa = fmaf(hv.y, wv4.y, aa);
                    aa = fmaf(hv.z, wv4.z, aa); aa = fmaf(hv.w, wv4.w, aa);
                }
                aa += dpp_mov<DPP_XOR1>(aa);
                aa += dpp_mov<DPP_XOR2>(aa);
                aa += dpp_mov<DPP_HMIR>(aa);
                if (l8 == 0) {
                    const int st = cb + sl;
                    const int sO = dir ? (SS - 1 - st) : st;
                    sc_part[(((size_t)b * 2 + dir) * NF + f) * SS + sO] = aa;
                }
            }
            // (c) issue loads for chunk+2
            if (step + CH + 1 < SS) {
                const int nchunk = (step >> 4) + 2;
#pragma unroll
                for (int j3 = 0; j3 < 3; ++j3) {
                    const int flat4 = j3 * 512 + tid;
                    const int sc = flat4 / 96, w4 = flat4 % 96;
                    const int st2 = nchunk * CH + sc;
                    const int s2 = dir ? (SS - 1 - st2) : st2;
                    pf[j3] = *reinterpret_cast<const float4*>(xg_bd + (size_t)s2 * 768 + w4 * 4);
                }
            }
        }
    }
}

// ---------------------------------------------------------------------------
// Kernel 4: time attention v2 (unchanged from R15).
// ---------------------------------------------------------------------------
__global__ __launch_bounds__(512) void k_attn2(
    const float* __restrict__ states,   // [B*S, 256]
    const float* __restrict__ sc_part,  // [B, 2, NF, SS]
    const float* __restrict__ c2b,      // [3]
    const float* __restrict__ demoip,   // [B, 3]
    const float* __restrict__ lin_w,    // [2, 771]
    const float* __restrict__ lin_b,    // [2]
    float* __restrict__ out,            // [B, 2]
    float* __restrict__ alpha_out,      // [B, 3, 128]
    float* __restrict__ ctx_out)        // [B, 768]
{
    const int b    = blockIdx.x;
    const int t    = threadIdx.x;      // 0..511
    const int lane = t & 63;
    const int wv   = t >> 6;

    __shared__ float sc[NF * SS];
    __shared__ float al[NF * SS];
    __shared__ float pbuf[8][NF * 256];   // 24 KB partials
    __shared__ float ctx[768];

    const float* st = states + (size_t)b * SS * 256;

    if (t < NF * SS) {
        const int f = t >> 7, s = t & 127;
        sc[t] = sc_part[(((size_t)b * 2 + 0) * NF + f) * SS + s]
              + sc_part[(((size_t)b * 2 + 1) * NF + f) * SS + s]
              + c2b[f];
    }
    __syncthreads();

    if (wv < NF) {
        const float v0 = sc[wv * SS + lane], v1 = sc[wv * SS + 64 + lane];
        float mx = fmaxf(v0, v1);
#pragma unroll
        for (int m = 32; m >= 1; m >>= 1) mx = fmaxf(mx, __shfl_xor(mx, m));
        const float e0 = __expf(v0 - mx), e1 = __expf(v1 - mx);
        float sm = e0 + e1;
#pragma unroll
        for (int m = 32; m >= 1; m >>= 1) sm += __shfl_xor(sm, m);
        const float r = 1.f / sm;
        al[wv * SS + lane]      = e0 * r;
        al[wv * SS + 64 + lane] = e1 * r;
        alpha_out[((size_t)b * NF + wv) * SS + lane]      = e0 * r;
        alpha_out[((size_t)b * NF + wv) * SS + 64 + lane] = e1 * r;
    }
    __syncthreads();

    {
        const int grp = t >> 6, h4 = t & 63;
        float4 c0 = {0,0,0,0}, c1 = {0,0,0,0}, c2 = {0,0,0,0};
#pragma unroll 4
        for (int i = 0; i < 16; ++i) {
            const int s = grp * 16 + i;
            const float4 sv = *reinterpret_cast<const float4*>(st + (size_t)s * 256 + h4 * 4);
            const float a0 = al[s], a1 = al[SS + s], a2 = al[2 * SS + s];
            c0.x = fmaf(a0, sv.x, c0.x); c0.y = fmaf(a0, sv.y, c0.y);
            c0.z = fmaf(a0, sv.z, c0.z); c0.w = fmaf(a0, sv.w, c0.w);
            c1.x = fmaf(a1, sv.x, c1.x); c1.y = fmaf(a1, sv.y, c1.y);
            c1.z = fmaf(a1, sv.z, c1.z); c1.w = fmaf(a1, sv.w, c1.w);
            c2.x = fmaf(a2, sv.x, c2.x); c2.y = fmaf(a2, sv.y, c2.y);
            c2.z = fmaf(a2, sv.z, c2.z); c2.w = fmaf(a2, sv.w, c2.w);
        }
        *reinterpret_cast<float4*>(&pbuf[grp][0 * 256 + h4 * 4]) = c0;
        *reinterpret_cast<float4*>(&pbuf[grp][1 * 256 + h4 * 4]) = c1;
        *reinterpret_cast<float4*>(&pbuf[grp][2 * 256 + h4 * 4]) = c2;
    }
    __syncthreads();

    for (int o = t; o < 768; o += 512) {
        float v = 0.f;
#pragma unroll
        for (int k = 0; k < 8; ++k) v += pbuf[k][o];
        ctx[o] = v;
        ctx_out[(size_t)b * 768 + o] = v;
    }
    __syncthreads();

    if (wv == 0) {
        const float* lw0 = lin_w;          // row 0
        const float* lw1 = lin_w + 771;    // row 1
        float a0 = 0.f, a1 = 0.f;
#pragma unroll 4
        for (int i = lane; i < 768; i += 64) {
            const float c = ctx[i];
            a0 = fmaf(c, lw0[i], a0);
            a1 = fmaf(c, lw1[i], a1);
        }
#pragma unroll
        for (int m = 32; m >= 1; m >>= 1) {
            a0 += __shfl_xor(a0, m);
            a1 += __shfl_xor(a1, m);
        }
        if (lane == 0) {
            a0 += lin_b[0]; a1 += lin_b[1];
            for (int k = 0; k < 3; ++k) {
                const float d = demoip[b * 3 + k];
                a0 = fmaf(d, lw0[768 + k], a0);
                a1 = fmaf(d, lw1[768 + k], a1);
            }
            const float m  = fmaxf(a0, a1);
            const float e0 = __expf(a0 - m), e1 = __expf(a1 - m);
            const float s  = e0 + e1;
            out[b * 2 + 0] = e0 / s;
            out[b * 2 + 1] = e1 / s;
        }
    }
}

// ---------------------------------------------------------------------------
extern "C" void kernel_launch(void* const* d_in, const int* in_sizes, int n_in,
                              void* d_out, int out_size, void* d_ws, size_t ws_size,
                              hipStream_t stream) {
    const float* inp     = (const float*)d_in[0];
    const float* demoip  = (const float*)d_in[1];
    const float* conv_w  = (const float*)d_in[2];
    const float* conv_b  = (const float*)d_in[3];
    const float* c2w     = (const float*)d_in[4];
    const float* c2b     = (const float*)d_in[5];
    const float* Wih_f   = (const float*)d_in[6];
    const float* Whh_f   = (const float*)d_in[7];
    const float* bih_f   = (const float*)d_in[8];
    const float* bhh_f   = (const float*)d_in[9];
    const float* Wih_b   = (const float*)d_in[10];
    const float* Whh_b   = (const float*)d_in[11];
    const float* bih_b   = (const float*)d_in[12];
    const float* bhh_b   = (const float*)d_in[13];
    const float* lin_w   = (const float*)d_in[14];
    const float* lin_b   = (const float*)d_in[15];

    // d_out layout: out[64] | alpha[12288] | states[1048576] | context[24576] | conv_wts[262144]
    float* out      = (float*)d_out;
    float* alpha    = out + 64;
    float* states   = out + 12352;
    float* context  = out + 1060928;
    float* conv_wts = out + 1085504;

    // workspace (16 MiB): [0,2MiB) conv_bf16 | [2MiB,4MiB) sc_part | [4MiB,16MiB) xg
    float* wsf            = (float*)d_ws;
    unsigned short* cbf   = (unsigned short*)d_ws;
    float* sc_part        = wsf + 524288;         // +2 MiB
    float* xg             = wsf + 1048576;        // +4 MiB

    k_pool<<<dim3(BB * SS), dim3(256), 0, stream>>>(inp, conv_w, conv_b, cbf, conv_wts);
    k_xg<<<dim3(16, 48), dim3(256), 0, stream>>>(cbf, Wih_f, Wih_b, bih_f, bih_b, xg);
    k_gru<<<dim3(64), dim3(512), 0, stream>>>(xg, Whh_f, Whh_b, bhh_f, bhh_b, c2w, states, sc_part);
    k_attn2<<<dim3(BB), dim3(512), 0, stream>>>(states, sc_part, c2b, demoip, lin_w, lin_b, out, alpha, context);
}